// Round 4
// baseline (51.121 us; speedup 1.0000x reference)
//
#include <hip/hip_runtime.h>

#define SGRID 14
#define L_COORD 5.0f
#define L_NOOBJ 0.5f
#define BCELLS 192           // 3 waves/block; LDS ~40KB -> 4 blocks/CU
#define RTHREADS 256

// ws layout: offset 0: int fmt flag; offset 256: float4 partial[nblocks]

__global__ __launch_bounds__(256) void detect_init(const unsigned int* __restrict__ m,
                                                   int n_uints, int* __restrict__ fmt_flag) {
    __shared__ int found_s;
    if (threadIdx.x == 0) found_s = 0;
    __syncthreads();
    int found = 0;
    int base = threadIdx.x * 16;
    #pragma unroll
    for (int k = 0; k < 16; ++k) {
        int i = base + k;
        if (i < n_uints && m[i] > 1u) found = 1;
    }
    if (found) atomicOr(&found_s, 1);
    __syncthreads();
    if (threadIdx.x == 0) *fmt_flag = found_s;
}

__global__ __launch_bounds__(BCELLS) void yolo_main(const float* __restrict__ pred,
                                                    const float* __restrict__ tbox,
                                                    const float* __restrict__ tcls,
                                                    const void* __restrict__ maskp,
                                                    const int* __restrict__ fmt_flag,
                                                    float4* __restrict__ partial,
                                                    int n_cells) {
    __shared__ float sp[BCELLS * 31];        // pred, padded stride 31 (gcd(31,32)=1, conflict-free reads)
    __shared__ float sc[BCELLS * 21];        // tcls, padded stride 21 (gcd(21,32)=1)
    __shared__ unsigned char sm[BCELLS];
    __shared__ float sred[BCELLS / 64][4];

    const int t = threadIdx.x;
    const int base = blockIdx.x * BCELLS;
    const int nblk = min(BCELLS, n_cells - base);

    const bool bytefmt = (*fmt_flag != 0);
    bool mymask = false;
    if (t < nblk) {
        mymask = bytefmt ? (((const unsigned char*)maskp)[base + t] != 0)
                         : (((const int*)maskp)[base + t] != 0);
    }
    if (t < BCELLS) sm[t] = mymask ? 1 : 0;

    float4 tb = make_float4(0.f, 0.f, 0.f, 0.f);
    if (mymask) tb = ((const float4*)tbox)[base + t];

    __syncthreads();

    // ---- stage pred: coalesced float4, scatter into padded LDS ----
    const float4* gp = (const float4*)(pred + (size_t)base * 30);
    const int npred4 = (nblk * 30) / 4;          // nblk always even here -> exact
    for (int f = t; f < npred4; f += BCELLS) {
        float4 v = gp[f];
        int e = f * 4;
        sp[(e / 30) * 31 + e % 30] = v.x; e++;
        sp[(e / 30) * 31 + e % 30] = v.y; e++;
        sp[(e / 30) * 31 + e % 30] = v.z; e++;
        sp[(e / 30) * 31 + e % 30] = v.w;
    }

    // ---- stage tcls: each float4 maps to exactly one cell (5 per cell); skip unmasked ----
    const float4* gc = (const float4*)(tcls + (size_t)base * 20);
    const int ncls4 = nblk * 5;
    for (int f = t; f < ncls4; f += BCELLS) {
        int cc = f / 5;
        if (sm[cc]) {
            float4 v = gc[f];
            int rb = cc * 21 + (f - cc * 5) * 4;
            sc[rb + 0] = v.x; sc[rb + 1] = v.y; sc[rb + 2] = v.z; sc[rb + 3] = v.w;
        }
    }
    __syncthreads();

    // ---- per-cell compute from LDS ----
    float reg = 0.f, contain = 0.f, noobj = 0.f, cls = 0.f;
    if (t < nblk) {
        const float* prow = &sp[t * 31];
        constexpr float invS = 1.0f / (float)SGRID;
        constexpr float sA = invS + 0.5f;

        if (mymask) {
            float tx1 = tb.x * invS - 0.5f * tb.z;
            float ty1 = tb.y * invS - 0.5f * tb.w;
            float tx2 = tb.z * sA;
            float ty2 = tb.w * sA;
            float ta = (tx2 - tx1) * (ty2 - ty1);

            float bx1[2], by1[2], bx2[2], by2[2], conf[2], iou[2];
            #pragma unroll
            for (int b = 0; b < 2; ++b) {
                float x = prow[b * 5 + 0], y = prow[b * 5 + 1];
                float w = prow[b * 5 + 2], h = prow[b * 5 + 3];
                conf[b] = prow[b * 5 + 4];
                bx1[b] = x * invS - 0.5f * w;
                by1[b] = y * invS - 0.5f * h;
                bx2[b] = w * sA;
                by2[b] = h * sA;
                float ltx = fmaxf(bx1[b], tx1), lty = fmaxf(by1[b], ty1);
                float rbx = fminf(bx2[b], tx2), rby = fminf(by2[b], ty2);
                float iw = fmaxf(rbx - ltx, 0.f), ih = fmaxf(rby - lty, 0.f);
                float inter = iw * ih;
                float a1 = (bx2[b] - bx1[b]) * (by2[b] - by1[b]);
                iou[b] = inter / (a1 + ta - inter);
            }
            int idx = (iou[1] > iou[0]) ? 1 : 0;       // jnp.argmax: first max wins on tie
            float biou = fmaxf(iou[0], iou[1]);

            float dx = tx1 - bx1[idx], dy = ty1 - by1[idx];
            float dxy = dx * dx + dy * dy;
            float sw = sqrtf(tx2) - sqrtf(bx2[idx]);
            float sh = sqrtf(ty2) - sqrtf(by2[idx]);
            float dwh = sw * sw + sh * sh;
            reg = L_COORD * (dxy + dwh);

            float dc = conf[idx] - biou;
            contain = dc * dc;

            const float* crow = &sc[t * 21];
            float c = 0.f;
            #pragma unroll
            for (int j = 0; j < 20; ++j) {
                float d = prow[10 + j] - crow[j];
                c += d * d;
            }
            cls = c;
        } else {
            float c0 = prow[4], c1 = prow[9];
            noobj = L_NOOBJ * (c0 * c0 + c1 * c1);
        }
    }

    // ---- wave(64) reduce, then cross-wave via LDS ----
    #pragma unroll
    for (int off = 32; off > 0; off >>= 1) {
        reg     += __shfl_down(reg, off, 64);
        contain += __shfl_down(contain, off, 64);
        noobj   += __shfl_down(noobj, off, 64);
        cls     += __shfl_down(cls, off, 64);
    }
    int wid = threadIdx.x >> 6, lane = threadIdx.x & 63;
    if (lane == 0) { sred[wid][0] = reg; sred[wid][1] = contain; sred[wid][2] = noobj; sred[wid][3] = cls; }
    __syncthreads();
    if (threadIdx.x == 0) {
        float r = 0.f, c = 0.f, n = 0.f, cl = 0.f;
        #pragma unroll
        for (int w = 0; w < BCELLS / 64; ++w) { r += sred[w][0]; c += sred[w][1]; n += sred[w][2]; cl += sred[w][3]; }
        partial[blockIdx.x] = make_float4(r, c, n, cl);   // contention-free store
    }
}

__global__ __launch_bounds__(RTHREADS) void reduce_final(const float4* __restrict__ partial,
                                                         int nparts,
                                                         float* __restrict__ out, float invN) {
    double r = 0.0, c = 0.0, n = 0.0, cl = 0.0;
    for (int k = threadIdx.x; k < nparts; k += RTHREADS) {
        float4 v = partial[k];
        r += v.x; c += v.y; n += v.z; cl += v.w;
    }
    #pragma unroll
    for (int off = 32; off > 0; off >>= 1) {
        r  += __shfl_down(r, off, 64);
        c  += __shfl_down(c, off, 64);
        n  += __shfl_down(n, off, 64);
        cl += __shfl_down(cl, off, 64);
    }
    __shared__ double sred[4][4];
    int wid = threadIdx.x >> 6, lane = threadIdx.x & 63;
    if (lane == 0) { sred[wid][0] = r; sred[wid][1] = c; sred[wid][2] = n; sred[wid][3] = cl; }
    __syncthreads();
    if (threadIdx.x == 0) {
        double R = 0.0, C = 0.0, Nn = 0.0, Cl = 0.0;
        #pragma unroll
        for (int w = 0; w < 4; ++w) { R += sred[w][0]; C += sred[w][1]; Nn += sred[w][2]; Cl += sred[w][3]; }
        double total = R + C + Nn + Cl;
        out[0] = (float)(total * (double)invN);
        out[1] = (float)(R * (double)invN);
        out[2] = (float)(C * (double)invN);
        out[3] = (float)(Nn * (double)invN);
        out[4] = (float)(Cl * (double)invN);
    }
}

extern "C" void kernel_launch(void* const* d_in, const int* in_sizes, int n_in,
                              void* d_out, int out_size, void* d_ws, size_t ws_size,
                              hipStream_t stream) {
    const float* pred = (const float*)d_in[0];
    const float* tbox = (const float*)d_in[1];
    const float* tcls = (const float*)d_in[2];
    const void*  mask = d_in[3];
    int n_cells = in_sizes[3];               // N * S * S
    int N = n_cells / (SGRID * SGRID);

    int* fmt = (int*)d_ws;
    float4* partial = (float4*)((char*)d_ws + 256);

    int n_uints = n_cells / 4;               // safe length in both mask layouts
    if (n_uints > 4096) n_uints = 4096;
    detect_init<<<1, 256, 0, stream>>>((const unsigned int*)mask, n_uints, fmt);

    int blocks = (n_cells + BCELLS - 1) / BCELLS;
    yolo_main<<<blocks, BCELLS, 0, stream>>>(pred, tbox, tcls, mask, fmt, partial, n_cells);

    reduce_final<<<1, RTHREADS, 0, stream>>>(partial, blocks, (float*)d_out, 1.0f / (float)N);
}

// Round 5
// 37.798 us; speedup vs baseline: 1.3525x; 1.3525x over previous
//
#include <hip/hip_runtime.h>

#define SGRID 14
#define L_COORD 5.0f
#define L_NOOBJ 0.5f
#define NTHREADS 256
#define RTHREADS 256

// ws layout: offset 0: int fmt flag; offset 256: float4 partial[nblocks]

__global__ __launch_bounds__(256) void detect_init(const unsigned int* __restrict__ m,
                                                   int n_uints, int* __restrict__ fmt_flag) {
    __shared__ int found_s;
    if (threadIdx.x == 0) found_s = 0;
    __syncthreads();
    int found = 0;
    int base = threadIdx.x * 16;
    #pragma unroll
    for (int k = 0; k < 16; ++k) {
        int i = base + k;
        if (i < n_uints && m[i] > 1u) found = 1;
    }
    if (found) atomicOr(&found_s, 1);
    __syncthreads();
    if (threadIdx.x == 0) *fmt_flag = found_s;
}

__global__ __launch_bounds__(NTHREADS) void yolo_main(const float* __restrict__ pred,
                                                      const float* __restrict__ tbox,
                                                      const float* __restrict__ tcls,
                                                      const void* __restrict__ maskp,
                                                      const int* __restrict__ fmt_flag,
                                                      float4* __restrict__ partial,
                                                      int n_cells) {
    float reg = 0.f, contain = 0.f, noobj = 0.f, cls = 0.f;
    const bool bytefmt = (*fmt_flag != 0);
    constexpr float invS = 1.0f / (float)SGRID;
    constexpr float sA = invS + 0.5f;

    const int cell = blockIdx.x * blockDim.x + threadIdx.x;   // 1 cell per thread
    if (cell < n_cells) {
        bool mask = bytefmt ? (((const unsigned char*)maskp)[cell] != 0)
                            : (((const int*)maskp)[cell] != 0);
        const float* p = pred + (size_t)cell * 30;

        if (mask) {
            float pv[30];
            #pragma unroll
            for (int k = 0; k < 15; ++k) {
                float2 v = ((const float2*)p)[k];
                pv[2 * k] = v.x; pv[2 * k + 1] = v.y;
            }
            float4 tb = ((const float4*)tbox)[cell];
            float tx1 = tb.x * invS - 0.5f * tb.z;
            float ty1 = tb.y * invS - 0.5f * tb.w;
            float tx2 = tb.z * sA;
            float ty2 = tb.w * sA;
            float ta = (tx2 - tx1) * (ty2 - ty1);

            float bx1[2], by1[2], bx2[2], by2[2], conf[2], iou[2];
            #pragma unroll
            for (int b = 0; b < 2; ++b) {
                float x = pv[b * 5 + 0], y = pv[b * 5 + 1];
                float w = pv[b * 5 + 2], h = pv[b * 5 + 3];
                conf[b] = pv[b * 5 + 4];
                bx1[b] = x * invS - 0.5f * w;
                by1[b] = y * invS - 0.5f * h;
                bx2[b] = w * sA;
                by2[b] = h * sA;
                float ltx = fmaxf(bx1[b], tx1), lty = fmaxf(by1[b], ty1);
                float rbx = fminf(bx2[b], tx2), rby = fminf(by2[b], ty2);
                float iw = fmaxf(rbx - ltx, 0.f), ih = fmaxf(rby - lty, 0.f);
                float inter = iw * ih;
                float a1 = (bx2[b] - bx1[b]) * (by2[b] - by1[b]);
                iou[b] = inter / (a1 + ta - inter);
            }
            int idx = (iou[1] > iou[0]) ? 1 : 0;       // jnp.argmax: first max wins on tie
            float biou = fmaxf(iou[0], iou[1]);

            float dx = tx1 - bx1[idx], dy = ty1 - by1[idx];
            float dxy = dx * dx + dy * dy;
            float sw = sqrtf(tx2) - sqrtf(bx2[idx]);
            float sh = sqrtf(ty2) - sqrtf(by2[idx]);
            float dwh = sw * sw + sh * sh;
            reg = L_COORD * (dxy + dwh);

            float dc = conf[idx] - biou;
            contain = dc * dc;

            const float4* tc = (const float4*)(tcls + (size_t)cell * 20);
            float c = 0.f;
            #pragma unroll
            for (int k = 0; k < 5; ++k) {
                float4 tt = tc[k];
                float d0 = pv[10 + 4 * k + 0] - tt.x;
                float d1 = pv[10 + 4 * k + 1] - tt.y;
                float d2 = pv[10 + 4 * k + 2] - tt.z;
                float d3 = pv[10 + 4 * k + 3] - tt.w;
                c += d0 * d0 + d1 * d1 + d2 * d2 + d3 * d3;
            }
            cls = c;
        } else {
            float c0 = p[4], c1 = p[9];
            noobj = L_NOOBJ * (c0 * c0 + c1 * c1);
        }
    }

    // wave(64) reduce
    #pragma unroll
    for (int off = 32; off > 0; off >>= 1) {
        reg     += __shfl_down(reg, off, 64);
        contain += __shfl_down(contain, off, 64);
        noobj   += __shfl_down(noobj, off, 64);
        cls     += __shfl_down(cls, off, 64);
    }
    __shared__ float sred[NTHREADS / 64][4];
    int wid = threadIdx.x >> 6, lane = threadIdx.x & 63;
    if (lane == 0) { sred[wid][0] = reg; sred[wid][1] = contain; sred[wid][2] = noobj; sred[wid][3] = cls; }
    __syncthreads();
    if (threadIdx.x == 0) {
        float r = 0.f, c = 0.f, n = 0.f, cl = 0.f;
        #pragma unroll
        for (int w = 0; w < NTHREADS / 64; ++w) { r += sred[w][0]; c += sred[w][1]; n += sred[w][2]; cl += sred[w][3]; }
        partial[blockIdx.x] = make_float4(r, c, n, cl);   // contention-free store
    }
}

__global__ __launch_bounds__(RTHREADS) void reduce_final(const float4* __restrict__ partial,
                                                         int nparts,
                                                         float* __restrict__ out, float invN) {
    double r = 0.0, c = 0.0, n = 0.0, cl = 0.0;
    for (int k = threadIdx.x; k < nparts; k += RTHREADS) {
        float4 v = partial[k];
        r += v.x; c += v.y; n += v.z; cl += v.w;
    }
    #pragma unroll
    for (int off = 32; off > 0; off >>= 1) {
        r  += __shfl_down(r, off, 64);
        c  += __shfl_down(c, off, 64);
        n  += __shfl_down(n, off, 64);
        cl += __shfl_down(cl, off, 64);
    }
    __shared__ double sred[4][4];
    int wid = threadIdx.x >> 6, lane = threadIdx.x & 63;
    if (lane == 0) { sred[wid][0] = r; sred[wid][1] = c; sred[wid][2] = n; sred[wid][3] = cl; }
    __syncthreads();
    if (threadIdx.x == 0) {
        double R = 0.0, C = 0.0, Nn = 0.0, Cl = 0.0;
        #pragma unroll
        for (int w = 0; w < 4; ++w) { R += sred[w][0]; C += sred[w][1]; Nn += sred[w][2]; Cl += sred[w][3]; }
        double total = R + C + Nn + Cl;
        out[0] = (float)(total * (double)invN);
        out[1] = (float)(R * (double)invN);
        out[2] = (float)(C * (double)invN);
        out[3] = (float)(Nn * (double)invN);
        out[4] = (float)(Cl * (double)invN);
    }
}

extern "C" void kernel_launch(void* const* d_in, const int* in_sizes, int n_in,
                              void* d_out, int out_size, void* d_ws, size_t ws_size,
                              hipStream_t stream) {
    const float* pred = (const float*)d_in[0];
    const float* tbox = (const float*)d_in[1];
    const float* tcls = (const float*)d_in[2];
    const void*  mask = d_in[3];
    int n_cells = in_sizes[3];               // N * S * S
    int N = n_cells / (SGRID * SGRID);

    int* fmt = (int*)d_ws;
    float4* partial = (float4*)((char*)d_ws + 256);

    int n_uints = n_cells / 4;               // safe length in both mask layouts
    if (n_uints > 4096) n_uints = 4096;
    detect_init<<<1, 256, 0, stream>>>((const unsigned int*)mask, n_uints, fmt);

    int blocks = (n_cells + NTHREADS - 1) / NTHREADS;   // 1 cell/thread -> max TLP
    yolo_main<<<blocks, NTHREADS, 0, stream>>>(pred, tbox, tcls, mask, fmt, partial, n_cells);

    reduce_final<<<1, RTHREADS, 0, stream>>>(partial, blocks, (float*)d_out, 1.0f / (float)N);
}

// Round 6
// 30.828 us; speedup vs baseline: 1.6583x; 1.2261x over previous
//
#include <hip/hip_runtime.h>

#define SGRID 14
#define L_COORD 5.0f
#define L_NOOBJ 0.5f
#define NBLOCKS 1024
#define NTHREADS 256
#define RTHREADS 256

// ws layout: offset 0: float4 partial[NBLOCKS]

__global__ __launch_bounds__(NTHREADS) void yolo_main(const float* __restrict__ pred,
                                                      const float* __restrict__ tbox,
                                                      const float* __restrict__ tcls,
                                                      const void* __restrict__ maskp,
                                                      float4* __restrict__ partial,
                                                      int n_cells) {
    // ---- per-block mask-format self-detect: scan first 4KB (L2-broadcast, ~free) ----
    // byte layout -> packed bools, some uint > 1; int layout -> values 0/1.
    __shared__ int fmt_s;
    if (threadIdx.x == 0) fmt_s = 0;
    __syncthreads();
    {
        const uint4 mv = ((const uint4*)maskp)[threadIdx.x];   // 256*16B = 4KB, in-bounds (mask >= 802816 B)
        if ((mv.x | mv.y | mv.z | mv.w) > 1u) atomicOr(&fmt_s, 1);
    }
    __syncthreads();
    const bool bytefmt = (fmt_s != 0);

    float reg = 0.f, contain = 0.f, noobj = 0.f, cls = 0.f;
    constexpr float invS = 1.0f / (float)SGRID;
    constexpr float sA = invS + 0.5f;

    for (int cell = blockIdx.x * blockDim.x + threadIdx.x; cell < n_cells;
         cell += NBLOCKS * NTHREADS) {
        bool mask = bytefmt ? (((const unsigned char*)maskp)[cell] != 0)
                            : (((const int*)maskp)[cell] != 0);
        const float* p = pred + (size_t)cell * 30;

        if (mask) {
            float pv[30];
            #pragma unroll
            for (int k = 0; k < 15; ++k) {
                float2 v = ((const float2*)p)[k];
                pv[2 * k] = v.x; pv[2 * k + 1] = v.y;
            }
            float4 tb = ((const float4*)tbox)[cell];
            float tx1 = tb.x * invS - 0.5f * tb.z;
            float ty1 = tb.y * invS - 0.5f * tb.w;
            float tx2 = tb.z * sA;
            float ty2 = tb.w * sA;
            float ta = (tx2 - tx1) * (ty2 - ty1);

            float bx1[2], by1[2], bx2[2], by2[2], conf[2], iou[2];
            #pragma unroll
            for (int b = 0; b < 2; ++b) {
                float x = pv[b * 5 + 0], y = pv[b * 5 + 1];
                float w = pv[b * 5 + 2], h = pv[b * 5 + 3];
                conf[b] = pv[b * 5 + 4];
                bx1[b] = x * invS - 0.5f * w;
                by1[b] = y * invS - 0.5f * h;
                bx2[b] = w * sA;
                by2[b] = h * sA;
                float ltx = fmaxf(bx1[b], tx1), lty = fmaxf(by1[b], ty1);
                float rbx = fminf(bx2[b], tx2), rby = fminf(by2[b], ty2);
                float iw = fmaxf(rbx - ltx, 0.f), ih = fmaxf(rby - lty, 0.f);
                float inter = iw * ih;
                float a1 = (bx2[b] - bx1[b]) * (by2[b] - by1[b]);
                iou[b] = inter / (a1 + ta - inter);
            }
            int idx = (iou[1] > iou[0]) ? 1 : 0;       // jnp.argmax: first max wins on tie
            float biou = fmaxf(iou[0], iou[1]);

            float dx = tx1 - bx1[idx], dy = ty1 - by1[idx];
            float dxy = dx * dx + dy * dy;
            float sw = sqrtf(tx2) - sqrtf(bx2[idx]);
            float sh = sqrtf(ty2) - sqrtf(by2[idx]);
            float dwh = sw * sw + sh * sh;
            reg += L_COORD * (dxy + dwh);

            float dc = conf[idx] - biou;
            contain += dc * dc;

            const float4* tc = (const float4*)(tcls + (size_t)cell * 20);
            float c = 0.f;
            #pragma unroll
            for (int k = 0; k < 5; ++k) {
                float4 tt = tc[k];
                float d0 = pv[10 + 4 * k + 0] - tt.x;
                float d1 = pv[10 + 4 * k + 1] - tt.y;
                float d2 = pv[10 + 4 * k + 2] - tt.z;
                float d3 = pv[10 + 4 * k + 3] - tt.w;
                c += d0 * d0 + d1 * d1 + d2 * d2 + d3 * d3;
            }
            cls += c;
        } else {
            float c0 = p[4], c1 = p[9];
            noobj += L_NOOBJ * (c0 * c0 + c1 * c1);
        }
    }

    // wave(64) reduce
    #pragma unroll
    for (int off = 32; off > 0; off >>= 1) {
        reg     += __shfl_down(reg, off, 64);
        contain += __shfl_down(contain, off, 64);
        noobj   += __shfl_down(noobj, off, 64);
        cls     += __shfl_down(cls, off, 64);
    }
    __shared__ float sred[NTHREADS / 64][4];
    int wid = threadIdx.x >> 6, lane = threadIdx.x & 63;
    if (lane == 0) { sred[wid][0] = reg; sred[wid][1] = contain; sred[wid][2] = noobj; sred[wid][3] = cls; }
    __syncthreads();
    if (threadIdx.x == 0) {
        float r = 0.f, c = 0.f, n = 0.f, cl = 0.f;
        #pragma unroll
        for (int w = 0; w < NTHREADS / 64; ++w) { r += sred[w][0]; c += sred[w][1]; n += sred[w][2]; cl += sred[w][3]; }
        partial[blockIdx.x] = make_float4(r, c, n, cl);   // contention-free store
    }
}

__global__ __launch_bounds__(RTHREADS) void reduce_final(const float4* __restrict__ partial,
                                                         float* __restrict__ out, float invN) {
    double r = 0.0, c = 0.0, n = 0.0, cl = 0.0;
    #pragma unroll
    for (int k = 0; k < NBLOCKS / RTHREADS; ++k) {
        float4 v = partial[threadIdx.x + k * RTHREADS];
        r += v.x; c += v.y; n += v.z; cl += v.w;
    }
    #pragma unroll
    for (int off = 32; off > 0; off >>= 1) {
        r  += __shfl_down(r, off, 64);
        c  += __shfl_down(c, off, 64);
        n  += __shfl_down(n, off, 64);
        cl += __shfl_down(cl, off, 64);
    }
    __shared__ double sred[4][4];
    int wid = threadIdx.x >> 6, lane = threadIdx.x & 63;
    if (lane == 0) { sred[wid][0] = r; sred[wid][1] = c; sred[wid][2] = n; sred[wid][3] = cl; }
    __syncthreads();
    if (threadIdx.x == 0) {
        double R = 0.0, C = 0.0, Nn = 0.0, Cl = 0.0;
        #pragma unroll
        for (int w = 0; w < 4; ++w) { R += sred[w][0]; C += sred[w][1]; Nn += sred[w][2]; Cl += sred[w][3]; }
        double total = R + C + Nn + Cl;
        out[0] = (float)(total * (double)invN);
        out[1] = (float)(R * (double)invN);
        out[2] = (float)(C * (double)invN);
        out[3] = (float)(Nn * (double)invN);
        out[4] = (float)(Cl * (double)invN);
    }
}

extern "C" void kernel_launch(void* const* d_in, const int* in_sizes, int n_in,
                              void* d_out, int out_size, void* d_ws, size_t ws_size,
                              hipStream_t stream) {
    const float* pred = (const float*)d_in[0];
    const float* tbox = (const float*)d_in[1];
    const float* tcls = (const float*)d_in[2];
    const void*  mask = d_in[3];
    int n_cells = in_sizes[3];               // N * S * S
    int N = n_cells / (SGRID * SGRID);

    float4* partial = (float4*)d_ws;

    yolo_main<<<NBLOCKS, NTHREADS, 0, stream>>>(pred, tbox, tcls, mask, partial, n_cells);
    reduce_final<<<1, RTHREADS, 0, stream>>>(partial, (float*)d_out, 1.0f / (float)N);
}